// Round 1
// baseline (171.054 us; speedup 1.0000x reference)
//
#include <hip/hip_runtime.h>
#include <hip/hip_bf16.h>
#include <math.h>

#define NF 64
#define NC 16

typedef __bf16 bf16x8 __attribute__((ext_vector_type(8)));
typedef float f32x4 __attribute__((ext_vector_type(4)));

// ---------------------------------------------------------------------------
// Kernel 1: per-component Cholesky + triangular inverse + constants.
// 16 blocks (one per component) x 64 threads (one wave).
// Outputs: g  = L^{-1} as bf16, row-major [NC][NF][NF]
//          t  = G*mu  fp32 [NC][NF]
//          Cc = log w_k - 0.5*d*log(2pi) - sum(log diag L)   fp32 [NC]
// ---------------------------------------------------------------------------
__global__ __launch_bounds__(64) void gmm_precompute(
    const float* __restrict__ cov,
    const float* __restrict__ means,
    const float* __restrict__ weights,
    __hip_bfloat16* __restrict__ g,
    float* __restrict__ t,
    float* __restrict__ Cc)
{
    const int k   = blockIdx.x;
    const int tid = threadIdx.x;   // 0..63, thread = matrix row (or column)

    __shared__ float Lm[NF][NF + 1];  // +1 pad: row stride 65 -> no bank conflicts
    __shared__ float X[NF][NF + 1];

    // load covariance row tid
    for (int j = 0; j < NF; ++j)
        Lm[tid][j] = cov[(k * NF + tid) * NF + j];
    __syncthreads();

    // right-looking Cholesky (lower). Rank-1 trailing updates are
    // independent per element -> no serial dependency chains.
    for (int j = 0; j < NF; ++j) {
        if (tid == j) Lm[j][j] = sqrtf(Lm[j][j]);
        __syncthreads();
        if (tid > j) Lm[tid][j] = Lm[tid][j] / Lm[j][j];
        __syncthreads();
        if (tid > j) {
            float lij = Lm[tid][j];
            for (int p = j + 1; p <= tid; ++p)
                Lm[tid][p] -= lij * Lm[p][j];
        }
        __syncthreads();
    }

    // X = L^{-1} by row sweep; thread tid owns column tid (reads only its
    // own column's earlier entries -> no cross-thread dependency).
    {
        const int c = tid;
        for (int i = 0; i < NF; ++i) {
            float s = (i == c) ? 1.0f : 0.0f;
            for (int p = 0; p < i; ++p)
                s -= Lm[i][p] * X[p][c];     // Lm[i][p] is a broadcast read
            X[i][c] = (i >= c) ? (s / Lm[i][i]) : 0.0f;
        }
    }
    __syncthreads();

    // write G row tid as bf16 (row-major; A-fragment reads are contiguous 16B)
    for (int j = 0; j < NF; ++j)
        g[(k * NF + tid) * NF + j] = __float2bfloat16(X[tid][j]);

    // t[i] = sum_j G[i][j] * mu[j]
    {
        float acc = 0.0f;
        for (int j = 0; j < NF; ++j)
            acc += X[tid][j] * means[k * NF + j];
        t[k * NF + tid] = acc;
    }

    // C_k
    {
        float ld = logf(Lm[tid][tid]);
        #pragma unroll
        for (int off = 1; off < 64; off <<= 1)
            ld += __shfl_xor(ld, off);
        if (tid == 0)
            Cc[k] = logf(weights[k]) - 0.5f * (float)NF * 1.8378770664093453f - ld;
    }
}

// ---------------------------------------------------------------------------
// Kernel 2: main GEMM + fused epilogue.
// One wave (64-thread block) per 64-sample tile.
// MFMA 16x16x32 bf16: A = G rows (m = G-row), B = samples (n = sample).
//   A lane l: row (l&15), k = (l>>4)*8 + j
//   B lane l: col (l&15), k = (l>>4)*8 + j
//   D lane l, reg r: row 4*(l>>4)+r, col (l&15)
// C-in is seeded with -t so D = z - t directly.
// ---------------------------------------------------------------------------
__global__ __launch_bounds__(64) void gmm_main(
    const float* __restrict__ data,
    const __hip_bfloat16* __restrict__ g,
    const float* __restrict__ t,
    const float* __restrict__ Cc,
    float* __restrict__ partials,
    int nTiles, int N)
{
    const int lane = threadIdx.x & 63;
    const int l15  = lane & 15;
    const int lg   = lane >> 4;
    const int tile = blockIdx.x;

    float wavePartial = 0.0f;

    if (tile < nTiles) {
        const long base = (long)tile * 64;

        // ---- load x fragments once (reused across all 16 components) ----
        bf16x8 xf[4][2];
        #pragma unroll
        for (int st = 0; st < 4; ++st) {
            long row = base + st * 16 + l15;
            if (row > (long)N - 1) row = (long)N - 1;
            const float* xp = data + row * NF + lg * 8;
            float4 a0 = *(const float4*)(xp);
            float4 a1 = *(const float4*)(xp + 4);
            float4 b0 = *(const float4*)(xp + 32);
            float4 b1 = *(const float4*)(xp + 36);
            bf16x8 f0, f1;
            f0[0] = (__bf16)a0.x; f0[1] = (__bf16)a0.y;
            f0[2] = (__bf16)a0.z; f0[3] = (__bf16)a0.w;
            f0[4] = (__bf16)a1.x; f0[5] = (__bf16)a1.y;
            f0[6] = (__bf16)a1.z; f0[7] = (__bf16)a1.w;
            f1[0] = (__bf16)b0.x; f1[1] = (__bf16)b0.y;
            f1[2] = (__bf16)b0.z; f1[3] = (__bf16)b0.w;
            f1[4] = (__bf16)b1.x; f1[5] = (__bf16)b1.y;
            f1[6] = (__bf16)b1.z; f1[7] = (__bf16)b1.w;
            xf[st][0] = f0;
            xf[st][1] = f1;
        }

        float m[4], s[4];
        #pragma unroll
        for (int st = 0; st < 4; ++st) { m[st] = -INFINITY; s[st] = 0.0f; }

        #pragma unroll 1
        for (int k = 0; k < NC; ++k) {
            float mah[4] = {0.0f, 0.0f, 0.0f, 0.0f};
            #pragma unroll
            for (int rc = 0; rc < 4; ++rc) {
                const __hip_bfloat16* grow = g + ((long)(k * NF + rc * 16 + l15)) * NF + lg * 8;
                bf16x8 ga = *(const bf16x8*)(grow);        // K-step 0 (k=0..31)
                bf16x8 gb = *(const bf16x8*)(grow + 32);   // K-step 1 (k=32..63)
                f32x4 tv = *(const f32x4*)(t + k * NF + rc * 16 + lg * 4);
                #pragma unroll
                for (int st = 0; st < 4; ++st) {
                    f32x4 acc;
                    acc[0] = -tv[0]; acc[1] = -tv[1];
                    acc[2] = -tv[2]; acc[3] = -tv[3];
                    acc = __builtin_amdgcn_mfma_f32_16x16x32_bf16(ga, xf[st][0], acc, 0, 0, 0);
                    acc = __builtin_amdgcn_mfma_f32_16x16x32_bf16(gb, xf[st][1], acc, 0, 0, 0);
                    mah[st] += acc[0] * acc[0];
                    mah[st] += acc[1] * acc[1];
                    mah[st] += acc[2] * acc[2];
                    mah[st] += acc[3] * acc[3];
                }
            }
            float Ck = Cc[k];
            #pragma unroll
            for (int st = 0; st < 4; ++st) {
                float v = mah[st];
                v += __shfl_xor(v, 16);
                v += __shfl_xor(v, 32);          // all lanes now hold full maha
                float wlp = fmaf(-0.5f, v, Ck);
                float mo = m[st];
                float mn = fmaxf(mo, wlp);
                s[st] = s[st] * __expf(mo - mn) + __expf(wlp - mn);
                m[st] = mn;
            }
        }

        // lanes 16..63 hold duplicates; count lanes 0..15 only
        if (lg == 0) {
            #pragma unroll
            for (int st = 0; st < 4; ++st) {
                long sid = base + st * 16 + l15;
                if (sid < (long)N)
                    wavePartial += m[st] + __logf(s[st]);
            }
        }
    }

    #pragma unroll
    for (int off = 1; off < 64; off <<= 1)
        wavePartial += __shfl_xor(wavePartial, off);
    if (lane == 0)
        partials[tile] = wavePartial;
}

// ---------------------------------------------------------------------------
// Kernel 3: deterministic final reduction (fixed order -> replay-stable).
// ---------------------------------------------------------------------------
__global__ __launch_bounds__(256) void gmm_reduce(
    const float* __restrict__ partials, int n, float* __restrict__ out)
{
    float s = 0.0f;
    for (int i = threadIdx.x; i < n; i += 256)
        s += partials[i];
    #pragma unroll
    for (int off = 1; off < 64; off <<= 1)
        s += __shfl_xor(s, off);
    __shared__ float sm[4];
    const int wave = threadIdx.x >> 6;
    const int lane = threadIdx.x & 63;
    if (lane == 0) sm[wave] = s;
    __syncthreads();
    if (threadIdx.x == 0)
        out[0] = (sm[0] + sm[1]) + (sm[2] + sm[3]);
}

// ---------------------------------------------------------------------------
extern "C" void kernel_launch(void* const* d_in, const int* in_sizes, int n_in,
                              void* d_out, int out_size, void* d_ws, size_t ws_size,
                              hipStream_t stream)
{
    const float* data    = (const float*)d_in[0];
    const float* weights = (const float*)d_in[1];
    const float* means   = (const float*)d_in[2];
    const float* cov     = (const float*)d_in[3];

    const int N = in_sizes[0] / NF;

    char* ws = (char*)d_ws;
    __hip_bfloat16* g = (__hip_bfloat16*)ws;                    // 16*64*64*2 = 131072 B
    float* t          = (float*)(ws + 131072);                  // 4096 B
    float* Cc         = (float*)(ws + 131072 + 4096);           // 64 B
    float* partials   = (float*)(ws + 131072 + 4096 + 64);      // nTiles * 4 B

    const int nTiles = (N + 63) / 64;

    gmm_precompute<<<NC, 64, 0, stream>>>(cov, means, weights, g, t, Cc);
    gmm_main<<<nTiles, 64, 0, stream>>>(data, g, t, Cc, partials, nTiles, N);
    gmm_reduce<<<1, 256, 0, stream>>>(partials, nTiles, (float*)d_out);
}

// Round 2
// 127.573 us; speedup vs baseline: 1.3408x; 1.3408x over previous
//
#include <hip/hip_runtime.h>
#include <hip/hip_bf16.h>
#include <math.h>

#define NF 64
#define NC 16

typedef __bf16 bf16x8 __attribute__((ext_vector_type(8)));
typedef float f32x4 __attribute__((ext_vector_type(4)));

// ---------------------------------------------------------------------------
// Kernel 1: per-component Cholesky + triangular inverse + constants.
// 16 blocks (one per component) x 64 threads.
// v2: latency-oriented rewrite.
//  - Cholesky-Crout (left-looking): per column j only READS of finalized
//    columns inside the loop (no RMW aliasing -> LDS reads pipeline),
//    one write + one barrier per column.
//  - Triangular inverse entirely in registers: thread c owns column c of
//    G = L^{-1}; L[i][p] broadcast via __shfl of register rows with
//    compile-time indices (full unroll) -> pure VALU chain, no LDS.
// Outputs: g  = L^{-1} bf16 row-major [NC][NF][NF]
//          t  = G*mu  fp32 [NC][NF]
//          Cc = log w_k - 0.5*d*log(2pi) - sum(log diag L)  fp32 [NC]
// ---------------------------------------------------------------------------
__global__ __launch_bounds__(64) void gmm_precompute(
    const float* __restrict__ cov,
    const float* __restrict__ means,
    const float* __restrict__ weights,
    __hip_bfloat16* __restrict__ g,
    float* __restrict__ t,
    float* __restrict__ Cc)
{
    const int k   = blockIdx.x;
    const int tid = threadIdx.x;   // 0..63

    __shared__ float Lm[NF][NF + 1];  // stride 65: conflict-free column access
    __shared__ float Xs[NF][NF + 1];

    // ---- coalesced load of covariance (float4, flat) ----
    {
        const float* src = cov + (long)k * NF * NF;
        #pragma unroll
        for (int it = 0; it < 16; ++it) {
            int flat = it * 256 + tid * 4;           // 4-aligned within a row
            float4 v = *(const float4*)(src + flat);
            int r = flat >> 6, cidx = flat & 63;
            Lm[r][cidx]     = v.x;
            Lm[r][cidx + 1] = v.y;
            Lm[r][cidx + 2] = v.z;
            Lm[r][cidx + 3] = v.w;
        }
    }
    __syncthreads();

    // ---- Cholesky-Crout: column j from read-only prior columns ----
    float logdiag = 0.0f;                 // uniform across lanes
    for (int j = 0; j < NF; ++j) {
        float s = Lm[tid][j];
        float s0 = 0.0f, s1 = 0.0f;
        int p = 0;
        for (; p + 1 < j; p += 2) {
            s0 += Lm[tid][p]     * Lm[j][p];      // per-lane + broadcast reads
            s1 += Lm[tid][p + 1] * Lm[j][p + 1];
        }
        if (p < j) s0 += Lm[tid][p] * Lm[j][p];
        s -= s0 + s1;
        float dj = __shfl(s, j);          // pivot from lane j
        dj = sqrtf(dj);
        logdiag += __logf(dj);            // uniform accumulate (no reduce later)
        float lij = (tid == j) ? dj : s / dj;
        if (tid >= j) Lm[tid][j] = lij;
        __syncthreads();
    }

    // ---- own row of L into registers (compile-time indices from here on) ----
    float lrow[NF];
    #pragma unroll
    for (int p = 0; p < NF; ++p) lrow[p] = Lm[tid][p];

    // ---- G = L^{-1}, thread c owns column c; pure register/VALU chain ----
    float x[NF];
    const int c = tid;
    #pragma unroll
    for (int i = 0; i < NF; ++i) {
        float s0 = (i == c) ? 1.0f : 0.0f;
        float s1 = 0.0f;
        #pragma unroll
        for (int p = 0; p < i; p += 2) {
            s0 -= __shfl(lrow[p], i) * x[p];           // readlane: L[i][p]
            if (p + 1 < i) s1 -= __shfl(lrow[p + 1], i) * x[p + 1];
        }
        float Lii = __shfl(lrow[i], i);
        float rd  = 1.0f / Lii;                         // uniform
        x[i] = (i >= c) ? (s0 + s1) * rd : 0.0f;
    }

    // ---- transpose through LDS for row-wise outputs ----
    __syncthreads();
    #pragma unroll
    for (int i = 0; i < NF; ++i) Xs[i][c] = x[i];
    __syncthreads();

    // g row tid, packed bf16x8 stores
    {
        __hip_bfloat16* grow = g + ((long)(k * NF + tid)) * NF;
        #pragma unroll
        for (int jb = 0; jb < 8; ++jb) {
            bf16x8 v;
            #pragma unroll
            for (int u = 0; u < 8; ++u)
                v[u] = (__bf16)Xs[tid][jb * 8 + u];
            *(bf16x8*)(grow + jb * 8) = v;
        }
    }

    // t[tid] = dot(G row tid, mu)
    {
        const float* mu = means + k * NF;
        float a0 = 0.0f, a1 = 0.0f;
        #pragma unroll
        for (int j = 0; j < NF; j += 2) {
            a0 += Xs[tid][j]     * mu[j];
            a1 += Xs[tid][j + 1] * mu[j + 1];
        }
        t[k * NF + tid] = a0 + a1;
    }

    if (tid == 0)
        Cc[k] = __logf(weights[k]) - 0.5f * (float)NF * 1.8378770664093453f - logdiag;
}

// ---------------------------------------------------------------------------
// Kernel 2: main GEMM + fused epilogue (unchanged this round).
// One wave per 64-sample tile. MFMA 16x16x32 bf16, A = G rows, B = samples.
// C-in seeded with -t so D = Gx - t directly.
// ---------------------------------------------------------------------------
__global__ __launch_bounds__(64) void gmm_main(
    const float* __restrict__ data,
    const __hip_bfloat16* __restrict__ g,
    const float* __restrict__ t,
    const float* __restrict__ Cc,
    float* __restrict__ partials,
    int nTiles, int N)
{
    const int lane = threadIdx.x & 63;
    const int l15  = lane & 15;
    const int lg   = lane >> 4;
    const int tile = blockIdx.x;

    float wavePartial = 0.0f;

    if (tile < nTiles) {
        const long base = (long)tile * 64;

        bf16x8 xf[4][2];
        #pragma unroll
        for (int st = 0; st < 4; ++st) {
            long row = base + st * 16 + l15;
            if (row > (long)N - 1) row = (long)N - 1;
            const float* xp = data + row * NF + lg * 8;
            float4 a0 = *(const float4*)(xp);
            float4 a1 = *(const float4*)(xp + 4);
            float4 b0 = *(const float4*)(xp + 32);
            float4 b1 = *(const float4*)(xp + 36);
            bf16x8 f0, f1;
            f0[0] = (__bf16)a0.x; f0[1] = (__bf16)a0.y;
            f0[2] = (__bf16)a0.z; f0[3] = (__bf16)a0.w;
            f0[4] = (__bf16)a1.x; f0[5] = (__bf16)a1.y;
            f0[6] = (__bf16)a1.z; f0[7] = (__bf16)a1.w;
            f1[0] = (__bf16)b0.x; f1[1] = (__bf16)b0.y;
            f1[2] = (__bf16)b0.z; f1[3] = (__bf16)b0.w;
            f1[4] = (__bf16)b1.x; f1[5] = (__bf16)b1.y;
            f1[6] = (__bf16)b1.z; f1[7] = (__bf16)b1.w;
            xf[st][0] = f0;
            xf[st][1] = f1;
        }

        float m[4], s[4];
        #pragma unroll
        for (int st = 0; st < 4; ++st) { m[st] = -INFINITY; s[st] = 0.0f; }

        #pragma unroll 1
        for (int k = 0; k < NC; ++k) {
            float mah[4] = {0.0f, 0.0f, 0.0f, 0.0f};
            #pragma unroll
            for (int rc = 0; rc < 4; ++rc) {
                const __hip_bfloat16* grow = g + ((long)(k * NF + rc * 16 + l15)) * NF + lg * 8;
                bf16x8 ga = *(const bf16x8*)(grow);
                bf16x8 gb = *(const bf16x8*)(grow + 32);
                f32x4 tv = *(const f32x4*)(t + k * NF + rc * 16 + lg * 4);
                #pragma unroll
                for (int st = 0; st < 4; ++st) {
                    f32x4 acc;
                    acc[0] = -tv[0]; acc[1] = -tv[1];
                    acc[2] = -tv[2]; acc[3] = -tv[3];
                    acc = __builtin_amdgcn_mfma_f32_16x16x32_bf16(ga, xf[st][0], acc, 0, 0, 0);
                    acc = __builtin_amdgcn_mfma_f32_16x16x32_bf16(gb, xf[st][1], acc, 0, 0, 0);
                    mah[st] += acc[0] * acc[0];
                    mah[st] += acc[1] * acc[1];
                    mah[st] += acc[2] * acc[2];
                    mah[st] += acc[3] * acc[3];
                }
            }
            float Ck = Cc[k];
            #pragma unroll
            for (int st = 0; st < 4; ++st) {
                float v = mah[st];
                v += __shfl_xor(v, 16);
                v += __shfl_xor(v, 32);
                float wlp = fmaf(-0.5f, v, Ck);
                float mo = m[st];
                float mn = fmaxf(mo, wlp);
                s[st] = s[st] * __expf(mo - mn) + __expf(wlp - mn);
                m[st] = mn;
            }
        }

        if (lg == 0) {
            #pragma unroll
            for (int st = 0; st < 4; ++st) {
                long sid = base + st * 16 + l15;
                if (sid < (long)N)
                    wavePartial += m[st] + __logf(s[st]);
            }
        }
    }

    #pragma unroll
    for (int off = 1; off < 64; off <<= 1)
        wavePartial += __shfl_xor(wavePartial, off);
    if (lane == 0)
        partials[tile] = wavePartial;
}

// ---------------------------------------------------------------------------
// Kernel 3: deterministic final reduction.
// ---------------------------------------------------------------------------
__global__ __launch_bounds__(256) void gmm_reduce(
    const float* __restrict__ partials, int n, float* __restrict__ out)
{
    float s = 0.0f;
    for (int i = threadIdx.x; i < n; i += 256)
        s += partials[i];
    #pragma unroll
    for (int off = 1; off < 64; off <<= 1)
        s += __shfl_xor(s, off);
    __shared__ float sm[4];
    const int wave = threadIdx.x >> 6;
    const int lane = threadIdx.x & 63;
    if (lane == 0) sm[wave] = s;
    __syncthreads();
    if (threadIdx.x == 0)
        out[0] = (sm[0] + sm[1]) + (sm[2] + sm[3]);
}

// ---------------------------------------------------------------------------
extern "C" void kernel_launch(void* const* d_in, const int* in_sizes, int n_in,
                              void* d_out, int out_size, void* d_ws, size_t ws_size,
                              hipStream_t stream)
{
    const float* data    = (const float*)d_in[0];
    const float* weights = (const float*)d_in[1];
    const float* means   = (const float*)d_in[2];
    const float* cov     = (const float*)d_in[3];

    const int N = in_sizes[0] / NF;

    char* ws = (char*)d_ws;
    __hip_bfloat16* g = (__hip_bfloat16*)ws;                    // 131072 B
    float* t          = (float*)(ws + 131072);                  // 4096 B
    float* Cc         = (float*)(ws + 131072 + 4096);           // 64 B
    float* partials   = (float*)(ws + 131072 + 4096 + 64);      // nTiles * 4 B

    const int nTiles = (N + 63) / 64;

    gmm_precompute<<<NC, 64, 0, stream>>>(cov, means, weights, g, t, Cc);
    gmm_main<<<nTiles, 64, 0, stream>>>(data, g, t, Cc, partials, nTiles, N);
    gmm_reduce<<<1, 256, 0, stream>>>(partials, nTiles, (float*)d_out);
}

// Round 3
// 118.756 us; speedup vs baseline: 1.4404x; 1.0742x over previous
//
#include <hip/hip_runtime.h>
#include <hip/hip_bf16.h>
#include <math.h>

#define NF 64
#define NC 16
#define WPB 4   // waves per block in gmm_main

typedef __bf16 bf16x8 __attribute__((ext_vector_type(8)));
typedef float f32x4 __attribute__((ext_vector_type(4)));
typedef unsigned int u32;

// async global->LDS, 16B per lane. LDS dest must be wave-uniform base.
__device__ __forceinline__ void stage16(const void* gsrc, void* ldst) {
    __builtin_amdgcn_global_load_lds(
        (const __attribute__((address_space(1))) u32*)gsrc,
        (__attribute__((address_space(3))) u32*)ldst,
        16, 0, 0);
}

// ---------------------------------------------------------------------------
// Kernel 1: per-component Cholesky + triangular inverse + constants.
// 16 blocks x 64 threads. v3: no __shfl in hot chains.
//  - Crout Cholesky in LDS (pad-65 rows; pivot via LDS scalar broadcast).
//  - L copied to 16B-aligned LT via conflict-free column transpose; inverse
//    forward-substitution reads LT rows as broadcast float4 LDS loads,
//    x[] entirely in registers with static indices.
// g is stored with chunk-XOR swizzle: chunk jb of row r lands at jb^(r&7),
// so gmm_main can global_load_lds linearly and ds_read with the same XOR.
// ---------------------------------------------------------------------------
__global__ __launch_bounds__(64) void gmm_precompute(
    const float* __restrict__ cov,
    const float* __restrict__ means,
    const float* __restrict__ weights,
    __hip_bfloat16* __restrict__ g,
    float* __restrict__ t,
    float* __restrict__ Cc)
{
    const int k   = blockIdx.x;
    const int tid = threadIdx.x;

    __shared__ float Lm[NF][NF + 1];          // pad 65: column access conflict-free
    __shared__ __align__(16) float LT[NF][NF]; // row-aligned for float4 broadcast
    __shared__ float piv;
    __shared__ float rdg[NF];

    // coalesced cov load
    {
        const float* src = cov + (long)k * NF * NF;
        #pragma unroll
        for (int it = 0; it < 16; ++it) {
            int flat = it * 256 + tid * 4;
            float4 v = *(const float4*)(src + flat);
            int r = flat >> 6, ci = flat & 63;
            Lm[r][ci] = v.x; Lm[r][ci + 1] = v.y;
            Lm[r][ci + 2] = v.z; Lm[r][ci + 3] = v.w;
        }
    }
    __syncthreads();

    // Crout Cholesky
    float logdiag = 0.0f;
    for (int j = 0; j < NF; ++j) {
        float s = Lm[tid][j];
        float s0 = 0.0f, s1 = 0.0f;
        int p = 0;
        for (; p + 1 < j; p += 2) {
            s0 += Lm[tid][p]     * Lm[j][p];
            s1 += Lm[tid][p + 1] * Lm[j][p + 1];
        }
        if (p < j) s0 += Lm[tid][p] * Lm[j][p];
        s -= s0 + s1;
        if (tid == j) piv = s;
        __syncthreads();
        float dj  = sqrtf(piv);
        float rdj = 1.0f / dj;
        logdiag += __logf(dj);
        if (tid == j) rdg[j] = rdj;
        if (tid >= j) Lm[tid][j] = (tid == j) ? dj : s * rdj;
        __syncthreads();
    }

    // LT = L (zeros above diag): lane owns column tid; column writes conflict-free
    #pragma unroll
    for (int p = 0; p < NF; ++p)
        LT[p][tid] = (p >= tid) ? Lm[p][tid] : 0.0f;
    __syncthreads();

    // forward substitution: thread c owns column c of G = L^{-1}
    const int c = tid;
    float x[NF];
    #pragma unroll
    for (int i = 0; i < NF; ++i) {
        float s0 = (i == c) ? 1.0f : 0.0f;
        float s1 = 0.0f;
        const float4* row4 = (const float4*)&LT[i][0];
        #pragma unroll
        for (int q = 0; q * 4 < i; ++q) {
            float4 v = row4[q];   // broadcast LDS read, 16B aligned
            int p = q * 4;
            if (p     < i) s0 -= v.x * x[p];
            if (p + 1 < i) s1 -= v.y * x[p + 1];
            if (p + 2 < i) s0 -= v.z * x[p + 2];
            if (p + 3 < i) s1 -= v.w * x[p + 3];
        }
        x[i] = (i >= c) ? (s0 + s1) * rdg[i] : 0.0f;
    }

    // transpose G through Lm (pad-65 column writes conflict-free)
    __syncthreads();
    #pragma unroll
    for (int i = 0; i < NF; ++i) Lm[i][c] = x[i];
    __syncthreads();

    // g row tid, bf16x8 chunks stored at XOR-swizzled chunk positions
    {
        __hip_bfloat16* grow = g + ((long)(k * NF + tid)) * NF;
        #pragma unroll
        for (int jb = 0; jb < 8; ++jb) {
            bf16x8 v;
            #pragma unroll
            for (int u = 0; u < 8; ++u)
                v[u] = (__bf16)Lm[tid][jb * 8 + u];
            *(bf16x8*)(grow + ((jb ^ (tid & 7)) * 8)) = v;
        }
    }

    // t[tid] = dot(G row tid, mu)
    {
        const float* mu = means + k * NF;
        float a0 = 0.0f, a1 = 0.0f;
        #pragma unroll
        for (int j = 0; j < NF; j += 2) {
            a0 += Lm[tid][j]     * mu[j];
            a1 += Lm[tid][j + 1] * mu[j + 1];
        }
        t[k * NF + tid] = a0 + a1;
    }

    if (tid == 0)
        Cc[k] = __logf(weights[k]) - 0.5f * (float)NF * 1.8378770664093453f - logdiag;
}

// ---------------------------------------------------------------------------
// Kernel 2: main GEMM + fused epilogue. 256-thread blocks (4 waves), each
// wave owns one 64-sample tile. Per component k: G-block (8 KB, pre-swizzled
// in global) staged to LDS via global_load_lds, double-buffered:
//   STAGE(buf^1, k+1) ; ds_read+MFMA on buf ; barrier ; swap.
// ds_read applies byte ^= (chunk^(row&7)) swizzle -> <=2-way bank aliasing.
// ---------------------------------------------------------------------------
__global__ __launch_bounds__(256) void gmm_main(
    const float* __restrict__ data,
    const char* __restrict__ gsw,         // swizzled bf16 G, [NC][8192 B]
    const float* __restrict__ t,
    const float* __restrict__ Cc,
    float* __restrict__ partials,
    int nTiles, int N)
{
    __shared__ __align__(16) char gbuf[2][8192];
    __shared__ float t_lds[NC * NF];
    __shared__ float cc_lds[NC];
    __shared__ float sm[WPB];

    const int tidx = threadIdx.x;
    const int w    = tidx >> 6;
    const int lane = tidx & 63;
    const int l15  = lane & 15;
    const int lg   = lane >> 4;

    // stage component 0 into buf 0 (async; lands by first barrier)
    {
        const char* src = gsw;
        #pragma unroll
        for (int i = 0; i < 2; ++i) {
            int off = (i * WPB + w) * 1024;
            stage16(src + off + lane * 16, &gbuf[0][off]);
        }
    }

    // t / Cc -> LDS
    {
        float4 tv = *(const float4*)(t + tidx * 4);
        *(float4*)&t_lds[tidx * 4] = tv;
        if (tidx < NC) cc_lds[tidx] = Cc[tidx];
    }

    // x fragments for this wave's tile (overlaps with stage-0 flight)
    const int tile = blockIdx.x * WPB + w;
    const long base = (long)tile * 64;
    bf16x8 xf[4][2];
    #pragma unroll
    for (int st = 0; st < 4; ++st) {
        long row = base + st * 16 + l15;
        if (row > (long)N - 1) row = (long)N - 1;
        const float* xp = data + row * NF + lg * 8;
        float4 a0 = *(const float4*)(xp);
        float4 a1 = *(const float4*)(xp + 4);
        float4 b0 = *(const float4*)(xp + 32);
        float4 b1 = *(const float4*)(xp + 36);
        bf16x8 f0, f1;
        f0[0] = (__bf16)a0.x; f0[1] = (__bf16)a0.y;
        f0[2] = (__bf16)a0.z; f0[3] = (__bf16)a0.w;
        f0[4] = (__bf16)a1.x; f0[5] = (__bf16)a1.y;
        f0[6] = (__bf16)a1.z; f0[7] = (__bf16)a1.w;
        f1[0] = (__bf16)b0.x; f1[1] = (__bf16)b0.y;
        f1[2] = (__bf16)b0.z; f1[3] = (__bf16)b0.w;
        f1[4] = (__bf16)b1.x; f1[5] = (__bf16)b1.y;
        f1[6] = (__bf16)b1.z; f1[7] = (__bf16)b1.w;
        xf[st][0] = f0;
        xf[st][1] = f1;
    }

    __syncthreads();   // stage-0 + t_lds complete

    // swizzled LDS byte offsets (static per lane)
    int offA[4], offB[4];
    #pragma unroll
    for (int rc = 0; rc < 4; ++rc) {
        int row = rc * 16 + l15;
        offA[rc] = row * 128 + ((lg       ^ (l15 & 7)) * 16);
        offB[rc] = row * 128 + (((lg + 4) ^ (l15 & 7)) * 16);
    }

    float m[4], s[4];
    #pragma unroll
    for (int st = 0; st < 4; ++st) { m[st] = -INFINITY; s[st] = 0.0f; }

    int cur = 0;
    #pragma unroll 1
    for (int k = 0; k < NC; ++k) {
        if (k + 1 < NC) {   // prefetch next component into the other buffer
            const char* src = gsw + (size_t)(k + 1) * 8192;
            #pragma unroll
            for (int i = 0; i < 2; ++i) {
                int off = (i * WPB + w) * 1024;
                stage16(src + off + lane * 16, &gbuf[cur ^ 1][off]);
            }
        }

        float mah[4] = {0.0f, 0.0f, 0.0f, 0.0f};
        #pragma unroll
        for (int rc = 0; rc < 4; ++rc) {
            bf16x8 ga = *(const bf16x8*)(&gbuf[cur][offA[rc]]);
            bf16x8 gb = *(const bf16x8*)(&gbuf[cur][offB[rc]]);
            f32x4 tv  = *(const f32x4*)(&t_lds[k * NF + rc * 16 + lg * 4]);
            #pragma unroll
            for (int st = 0; st < 4; ++st) {
                f32x4 acc;
                acc[0] = -tv[0]; acc[1] = -tv[1];
                acc[2] = -tv[2]; acc[3] = -tv[3];
                acc = __builtin_amdgcn_mfma_f32_16x16x32_bf16(ga, xf[st][0], acc, 0, 0, 0);
                acc = __builtin_amdgcn_mfma_f32_16x16x32_bf16(gb, xf[st][1], acc, 0, 0, 0);
                mah[st] += acc[0] * acc[0];
                mah[st] += acc[1] * acc[1];
                mah[st] += acc[2] * acc[2];
                mah[st] += acc[3] * acc[3];
            }
        }
        float Ck = cc_lds[k];
        #pragma unroll
        for (int st = 0; st < 4; ++st) {
            float v = mah[st];
            v += __shfl_xor(v, 16);
            v += __shfl_xor(v, 32);
            float wlp = fmaf(-0.5f, v, Ck);
            float mo = m[st];
            float mn = fmaxf(mo, wlp);
            s[st] = s[st] * __expf(mo - mn) + __expf(wlp - mn);
            m[st] = mn;
        }

        __syncthreads();   // drains stage(k+1); orders buffer reuse
        cur ^= 1;
    }

    // per-wave result (lanes lg==0 hold valid rows; others contribute 0)
    float wavePartial = 0.0f;
    if (lg == 0) {
        #pragma unroll
        for (int st = 0; st < 4; ++st) {
            long sid = base + st * 16 + l15;
            if (sid < (long)N)
                wavePartial += m[st] + __logf(s[st]);
        }
    }
    #pragma unroll
    for (int off = 1; off < 64; off <<= 1)
        wavePartial += __shfl_xor(wavePartial, off);
    if (lane == 0) sm[w] = wavePartial;
    __syncthreads();
    if (tidx == 0)
        partials[blockIdx.x] = (sm[0] + sm[1]) + (sm[2] + sm[3]);
}

// ---------------------------------------------------------------------------
// Kernel 3: deterministic final reduction.
// ---------------------------------------------------------------------------
__global__ __launch_bounds__(256) void gmm_reduce(
    const float* __restrict__ partials, int n, float* __restrict__ out)
{
    float s = 0.0f;
    for (int i = threadIdx.x; i < n; i += 256)
        s += partials[i];
    #pragma unroll
    for (int off = 1; off < 64; off <<= 1)
        s += __shfl_xor(s, off);
    __shared__ float sm[4];
    const int wave = threadIdx.x >> 6;
    const int lane = threadIdx.x & 63;
    if (lane == 0) sm[wave] = s;
    __syncthreads();
    if (threadIdx.x == 0)
        out[0] = (sm[0] + sm[1]) + (sm[2] + sm[3]);
}

// ---------------------------------------------------------------------------
extern "C" void kernel_launch(void* const* d_in, const int* in_sizes, int n_in,
                              void* d_out, int out_size, void* d_ws, size_t ws_size,
                              hipStream_t stream)
{
    const float* data    = (const float*)d_in[0];
    const float* weights = (const float*)d_in[1];
    const float* means   = (const float*)d_in[2];
    const float* cov     = (const float*)d_in[3];

    const int N = in_sizes[0] / NF;

    char* ws = (char*)d_ws;
    __hip_bfloat16* g = (__hip_bfloat16*)ws;                    // 131072 B (swizzled)
    float* t          = (float*)(ws + 131072);                  // 4096 B
    float* Cc         = (float*)(ws + 131072 + 4096);           // 64 B
    float* partials   = (float*)(ws + 131072 + 4096 + 64);      // nBlocks * 4 B

    const int nTiles  = (N + 63) / 64;
    const int nBlocks = (nTiles + WPB - 1) / WPB;

    gmm_precompute<<<NC, 64, 0, stream>>>(cov, means, weights, g, t, Cc);
    gmm_main<<<nBlocks, 64 * WPB, 0, stream>>>(data, (const char*)g, t, Cc, partials, nTiles, N);
    gmm_reduce<<<1, 256, 0, stream>>>(partials, nBlocks, (float*)d_out);
}

// Round 4
// 95.843 us; speedup vs baseline: 1.7847x; 1.2391x over previous
//
#include <hip/hip_runtime.h>
#include <hip/hip_bf16.h>
#include <math.h>

#define NF 64
#define NC 16
#define WPB 4   // waves per block in gmm_main

typedef __bf16 bf16x8 __attribute__((ext_vector_type(8)));
typedef float f32x4 __attribute__((ext_vector_type(4)));
typedef unsigned int u32;

// async global->LDS, 16B per lane. LDS dest must be wave-uniform base.
__device__ __forceinline__ void stage16(const void* gsrc, void* ldst) {
    __builtin_amdgcn_global_load_lds(
        (const __attribute__((address_space(1))) u32*)gsrc,
        (__attribute__((address_space(3))) u32*)ldst,
        16, 0, 0);
}

// ---------------------------------------------------------------------------
// Kernel 1 v4: symmetric rank-1 Cholesky, all-register.
// 16 blocks x 64 threads. Lane c owns column c of the trailing matrix in
// regs a[], accumulates row c of L in regs l[].
// Per step j (fully unrolled, all indices static):
//   every lane writes ONE float w[c] = a[j]  (row j == col j by symmetry)
//   barrier; d = w[j] (broadcast); l[j] = a[j]/sqrt(d);
//   a[i] -= w[i] * (a[j]/d)  for i>j   -- independent FMAs, no dot chain.
// Triangular inverse: fully-unrolled forward substitution using
// v_readlane (__shfl with constant lane) on l[] -- no LDS in the chain.
// g stored with chunk-XOR swizzle (chunk jb of row r at jb^(r&7)) for
// gmm_main's conflict-free ds_read after linear global_load_lds.
// ---------------------------------------------------------------------------
__global__ __launch_bounds__(64) void gmm_precompute(
    const float* __restrict__ cov,
    const float* __restrict__ means,
    const float* __restrict__ weights,
    __hip_bfloat16* __restrict__ g,
    float* __restrict__ t,
    float* __restrict__ Cc)
{
    const int k = blockIdx.x;
    const int c = threadIdx.x;   // lane owns column c

    __shared__ float wbuf[2][NF];
    __shared__ float Xs[NF][NF + 1];

    // column c of cov into regs (lane-consecutive addresses per i -> coalesced)
    float a[NF];
    {
        const float* src = cov + (long)k * NF * NF + c;
        #pragma unroll
        for (int i = 0; i < NF; ++i)
            a[i] = src[i * NF];
    }

    float l[NF];
    float logdiag = 0.0f;

    #pragma unroll
    for (int j = 0; j < NF; ++j) {
        float* wb = wbuf[j & 1];
        wb[c] = a[j];
        __syncthreads();
        float d  = wb[j];                 // broadcast read
        float rd = 1.0f / d;
        float rs = 1.0f / sqrtf(d);
        logdiag += 0.5f * __logf(d);      // uniform across lanes
        l[j] = a[j] * rs;                 // L[c][j]
        float beta = a[j] * rd;
        #pragma unroll
        for (int i = j + 1; i < NF; ++i)
            a[i] = fmaf(-wb[i], beta, a[i]);   // independent updates
    }

    // forward substitution: lane c computes column c of G = L^{-1}.
    // L[i][p] = readlane(l[p], i), all indices compile-time.
    float x[NF];
    #pragma unroll
    for (int i = 0; i < NF; ++i) {
        float s0 = (i == c) ? 1.0f : 0.0f;
        float s1 = 0.0f;
        #pragma unroll
        for (int p = 0; p + 1 < i; p += 2) {
            s0 = fmaf(-__shfl(l[p],     i), x[p],     s0);
            s1 = fmaf(-__shfl(l[p + 1], i), x[p + 1], s1);
        }
        if (i & 1)
            s0 = fmaf(-__shfl(l[i - 1], i), x[i - 1], s0);
        float rdi = 1.0f / __shfl(l[i], i);
        x[i] = (i >= c) ? (s0 + s1) * rdi : 0.0f;
    }

    // transpose through LDS (pad-65 column writes conflict-free)
    __syncthreads();
    #pragma unroll
    for (int i = 0; i < NF; ++i) Xs[i][c] = x[i];
    __syncthreads();

    // g row c, bf16x8 chunks at XOR-swizzled chunk positions
    {
        __hip_bfloat16* grow = g + ((long)(k * NF + c)) * NF;
        #pragma unroll
        for (int jb = 0; jb < 8; ++jb) {
            bf16x8 v;
            #pragma unroll
            for (int u = 0; u < 8; ++u)
                v[u] = (__bf16)Xs[c][jb * 8 + u];
            *(bf16x8*)(grow + ((jb ^ (c & 7)) * 8)) = v;
        }
    }

    // t[c] = dot(G row c, mu)
    {
        const float* mu = means + k * NF;
        float a0 = 0.0f, a1 = 0.0f;
        #pragma unroll
        for (int j = 0; j < NF; j += 2) {
            a0 = fmaf(Xs[c][j],     mu[j],     a0);
            a1 = fmaf(Xs[c][j + 1], mu[j + 1], a1);
        }
        t[k * NF + c] = a0 + a1;
    }

    if (c == 0)
        Cc[k] = __logf(weights[k]) - 0.5f * (float)NF * 1.8378770664093453f - logdiag;
}

// ---------------------------------------------------------------------------
// Kernel 2 v4: main GEMM + fused epilogue. 256-thread blocks (4 waves), each
// wave one 64-sample tile. Components processed in PAIRS: each LDS buffer
// holds 2 components (16 KB); 8 double-buffered phases instead of 16 ->
// half the barrier/drain tax, 64 MFMA per phase.
// ---------------------------------------------------------------------------
__global__ __launch_bounds__(256) void gmm_main(
    const float* __restrict__ data,
    const char* __restrict__ gsw,         // swizzled bf16 G, [NC][8192 B]
    const float* __restrict__ t,
    const float* __restrict__ Cc,
    float* __restrict__ partials,
    int nTiles, int N)
{
    __shared__ __align__(16) char gbuf[2][16384];
    __shared__ float t_lds[NC * NF];
    __shared__ float cc_lds[NC];
    __shared__ float sm[WPB];

    const int tidx = threadIdx.x;
    const int w    = tidx >> 6;
    const int lane = tidx & 63;
    const int l15  = lane & 15;
    const int lg   = lane >> 4;

    // stage pair 0 (components 0,1) into buf 0
    #pragma unroll
    for (int i = 0; i < 4; ++i) {
        int off = (i * WPB + w) * 1024;
        stage16(gsw + off + lane * 16, &gbuf[0][off]);
    }

    // t / Cc -> LDS
    *(float4*)&t_lds[tidx * 4] = *(const float4*)(t + tidx * 4);
    if (tidx < NC) cc_lds[tidx] = Cc[tidx];

    // x fragments (overlap with stage-0 flight)
    const int tile = blockIdx.x * WPB + w;
    const long base = (long)tile * 64;
    bf16x8 xf[4][2];
    #pragma unroll
    for (int st = 0; st < 4; ++st) {
        long row = base + st * 16 + l15;
        if (row > (long)N - 1) row = (long)N - 1;
        const float* xp = data + row * NF + lg * 8;
        float4 a0 = *(const float4*)(xp);
        float4 a1 = *(const float4*)(xp + 4);
        float4 b0 = *(const float4*)(xp + 32);
        float4 b1 = *(const float4*)(xp + 36);
        bf16x8 f0, f1;
        f0[0] = (__bf16)a0.x; f0[1] = (__bf16)a0.y;
        f0[2] = (__bf16)a0.z; f0[3] = (__bf16)a0.w;
        f0[4] = (__bf16)a1.x; f0[5] = (__bf16)a1.y;
        f0[6] = (__bf16)a1.z; f0[7] = (__bf16)a1.w;
        f1[0] = (__bf16)b0.x; f1[1] = (__bf16)b0.y;
        f1[2] = (__bf16)b0.z; f1[3] = (__bf16)b0.w;
        f1[4] = (__bf16)b1.x; f1[5] = (__bf16)b1.y;
        f1[6] = (__bf16)b1.z; f1[7] = (__bf16)b1.w;
        xf[st][0] = f0;
        xf[st][1] = f1;
    }

    __syncthreads();   // stage-0 + t_lds complete

    // swizzled LDS byte offsets (static per lane)
    int offA[4], offB[4];
    #pragma unroll
    for (int rc = 0; rc < 4; ++rc) {
        int row = rc * 16 + l15;
        offA[rc] = row * 128 + ((lg       ^ (l15 & 7)) * 16);
        offB[rc] = row * 128 + (((lg + 4) ^ (l15 & 7)) * 16);
    }

    float m[4], s[4];
    #pragma unroll
    for (int st = 0; st < 4; ++st) { m[st] = -INFINITY; s[st] = 0.0f; }

    int cur = 0;
    #pragma unroll 1
    for (int it = 0; it < NC / 2; ++it) {
        if (it + 1 < NC / 2) {   // prefetch next pair
            const char* src = gsw + (size_t)(it + 1) * 16384;
            #pragma unroll
            for (int i = 0; i < 4; ++i) {
                int off = (i * WPB + w) * 1024;
                stage16(src + off + lane * 16, &gbuf[cur ^ 1][off]);
            }
        }

        float mah[2][4] = {{0.0f,0.0f,0.0f,0.0f},{0.0f,0.0f,0.0f,0.0f}};
        #pragma unroll
        for (int q = 0; q < 2; ++q) {
            #pragma unroll
            for (int rc = 0; rc < 4; ++rc) {
                bf16x8 ga = *(const bf16x8*)(&gbuf[cur][q * 8192 + offA[rc]]);
                bf16x8 gb = *(const bf16x8*)(&gbuf[cur][q * 8192 + offB[rc]]);
                f32x4 tv  = *(const f32x4*)(&t_lds[(it * 2 + q) * NF + rc * 16 + lg * 4]);
                #pragma unroll
                for (int st = 0; st < 4; ++st) {
                    f32x4 acc;
                    acc[0] = -tv[0]; acc[1] = -tv[1];
                    acc[2] = -tv[2]; acc[3] = -tv[3];
                    acc = __builtin_amdgcn_mfma_f32_16x16x32_bf16(ga, xf[st][0], acc, 0, 0, 0);
                    acc = __builtin_amdgcn_mfma_f32_16x16x32_bf16(gb, xf[st][1], acc, 0, 0, 0);
                    mah[q][st] += acc[0] * acc[0];
                    mah[q][st] += acc[1] * acc[1];
                    mah[q][st] += acc[2] * acc[2];
                    mah[q][st] += acc[3] * acc[3];
                }
            }
        }

        float Ck0 = cc_lds[it * 2];
        float Ck1 = cc_lds[it * 2 + 1];
        #pragma unroll
        for (int st = 0; st < 4; ++st) {
            float v0 = mah[0][st];
            v0 += __shfl_xor(v0, 16);
            v0 += __shfl_xor(v0, 32);
            float v1 = mah[1][st];
            v1 += __shfl_xor(v1, 16);
            v1 += __shfl_xor(v1, 32);
            float w0 = fmaf(-0.5f, v0, Ck0);
            float w1 = fmaf(-0.5f, v1, Ck1);
            float mo = m[st];
            float mn = fmaxf(fmaxf(mo, w0), w1);   // v_max3 shape
            s[st] = s[st] * __expf(mo - mn) + __expf(w0 - mn) + __expf(w1 - mn);
            m[st] = mn;
        }

        __syncthreads();   // drains stage(it+1); orders buffer reuse
        cur ^= 1;
    }

    // per-wave result (lanes lg==0 hold the 16 distinct sample-cols)
    float wavePartial = 0.0f;
    if (lg == 0) {
        #pragma unroll
        for (int st = 0; st < 4; ++st) {
            long sid = base + st * 16 + l15;
            if (sid < (long)N)
                wavePartial += m[st] + __logf(s[st]);
        }
    }
    #pragma unroll
    for (int off = 1; off < 64; off <<= 1)
        wavePartial += __shfl_xor(wavePartial, off);
    if (lane == 0) sm[w] = wavePartial;
    __syncthreads();
    if (tidx == 0)
        partials[blockIdx.x] = (sm[0] + sm[1]) + (sm[2] + sm[3]);
}

// ---------------------------------------------------------------------------
// Kernel 3: deterministic final reduction.
// ---------------------------------------------------------------------------
__global__ __launch_bounds__(256) void gmm_reduce(
    const float* __restrict__ partials, int n, float* __restrict__ out)
{
    float s = 0.0f;
    for (int i = threadIdx.x; i < n; i += 256)
        s += partials[i];
    #pragma unroll
    for (int off = 1; off < 64; off <<= 1)
        s += __shfl_xor(s, off);
    __shared__ float sm[4];
    const int wave = threadIdx.x >> 6;
    const int lane = threadIdx.x & 63;
    if (lane == 0) sm[wave] = s;
    __syncthreads();
    if (threadIdx.x == 0)
        out[0] = (sm[0] + sm[1]) + (sm[2] + sm[3]);
}

// ---------------------------------------------------------------------------
extern "C" void kernel_launch(void* const* d_in, const int* in_sizes, int n_in,
                              void* d_out, int out_size, void* d_ws, size_t ws_size,
                              hipStream_t stream)
{
    const float* data    = (const float*)d_in[0];
    const float* weights = (const float*)d_in[1];
    const float* means   = (const float*)d_in[2];
    const float* cov     = (const float*)d_in[3];

    const int N = in_sizes[0] / NF;

    char* ws = (char*)d_ws;
    __hip_bfloat16* g = (__hip_bfloat16*)ws;                    // 131072 B (swizzled)
    float* t          = (float*)(ws + 131072);                  // 4096 B
    float* Cc         = (float*)(ws + 131072 + 4096);           // 64 B
    float* partials   = (float*)(ws + 131072 + 4096 + 64);      // nBlocks * 4 B

    const int nTiles  = (N + 63) / 64;
    const int nBlocks = (nTiles + WPB - 1) / WPB;

    gmm_precompute<<<NC, 64, 0, stream>>>(cov, means, weights, g, t, Cc);
    gmm_main<<<nBlocks, 64 * WPB, 0, stream>>>(data, (const char*)g, t, Cc, partials, nTiles, N);
    gmm_reduce<<<1, 256, 0, stream>>>(partials, nBlocks, (float*)d_out);
}